// Round 1
// baseline (9916.639 us; speedup 1.0000x reference)
//
#include <hip/hip_runtime.h>
#include <hip/hip_fp16.h>

#define TL 3000
#define NN 30000
#define DIM 128
#define KNEG 75
#define NQ (2 * TL)
#define EPSF 1e-7f
#define MAXSQ 50.0f

__device__ __forceinline__ int wred_i(int v) {
#pragma unroll
  for (int o = 32; o > 0; o >>= 1) v += __shfl_xor(v, o, 64);
  return v;
}
__device__ __forceinline__ float wred_f(float v) {
#pragma unroll
  for (int o = 32; o > 0; o >>= 1) v += __shfl_xor(v, o, 64);
  return v;
}

// sqdist = min(K * acosh(max(-prod*c, 1+eps))^2, 50), K = 1/c
__device__ __forceinline__ float sqdist_f(float prod, float cv, float K) {
  float theta = fmaxf(-prod * cv, 1.0f + EPSF);
  float a = acoshf(theta);
  return fminf(K * a * a, MAXSQ);
}

__global__ void d_kernel(const float* __restrict__ emb, const float* __restrict__ c,
                         const int* __restrict__ links, float* __restrict__ D) {
  int i = blockIdx.x * blockDim.x + threadIdx.x;
  if (i >= TL) return;
  long l = links[2 * i];
  long r = links[2 * i + 1];
  const float* x = emb + l * DIM;
  const float* y = emb + r * DIM;
  float dot = 0.f;
  for (int k = 0; k < DIM; ++k) dot = fmaf(x[k], y[k], dot);
  float prod = dot - 2.0f * x[0] * y[0];  // -x0*y0 + sum_{1..127}
  float cv = c[0];
  float K = 1.0f / cv;
  D[i] = sqdist_f(prod, cv, K) + 1.0f;  // + GAMMA
}

__launch_bounds__(256)
__global__ void score_select_kernel(const float* __restrict__ emb,
                                    const float* __restrict__ c,
                                    const int* __restrict__ links,
                                    const float* __restrict__ D,
                                    float* __restrict__ out) {
  __shared__ __align__(16) float qvec[DIM];
  __shared__ unsigned short s16[NN];  // fp16 keys, 60000 B
  __shared__ int ish[4];

  const int q = blockIdx.x;
  const int tid = threadIdx.x;
  const int li = (q < TL) ? q : q - TL;
  const int node = (q < TL) ? links[2 * li] : links[2 * li + 1];
  const float Dq = D[li];
  const float cv = c[0];
  const float K = 1.0f / cv;

  if (tid < DIM) qvec[tid] = emb[(long)node * DIM + tid];
  __syncthreads();

  const float q0 = qvec[0];
  const float4* q4 = (const float4*)qvec;

  // --- score all 30000 embeddings, store fp16 keys in LDS ---
  for (int j = tid; j < NN; j += 256) {
    const float4* row = (const float4*)(emb + (long)j * DIM);
    float acc = 0.f;
    float e0 = 0.f;
#pragma unroll
    for (int k = 0; k < DIM / 4; ++k) {
      float4 e = row[k];
      float4 v = q4[k];
      if (k == 0) e0 = e.x;
      acc = fmaf(e.x, v.x, acc);
      acc = fmaf(e.y, v.y, acc);
      acc = fmaf(e.z, v.z, acc);
      acc = fmaf(e.w, v.w, acc);
    }
    float prod = acc - 2.0f * e0 * q0;
    float s = sqdist_f(prod, cv, K);
    s16[j] = __half_as_ushort(__float2half_rn(s));
  }
  __syncthreads();

  // --- bisection for T = 75th-smallest fp16 key (bit pattern monotone, s>=0) ---
  unsigned int lo = 0, hi = 0xFFFFu;
  while (lo < hi) {
    unsigned int mid = (lo + hi) >> 1;
    int cnt = 0;
    for (int j = tid; j < NN; j += 256) cnt += (s16[j] <= mid) ? 1 : 0;
    cnt = wred_i(cnt);
    if ((tid & 63) == 0) ish[tid >> 6] = cnt;
    __syncthreads();
    int tot = ish[0] + ish[1] + ish[2] + ish[3];
    if (tot >= KNEG) hi = mid; else lo = mid + 1;
    __syncthreads();
  }
  const unsigned int T = lo;
  const float Tval = __half2float(__ushort_as_half((unsigned short)T));

  // --- exact sum over the 75 smallest (ties at T weighted) ---
  __shared__ float fsh[4];
  int nl = 0;
  float sum = 0.f;
  for (int j = tid; j < NN; j += 256) {
    unsigned short k = s16[j];
    if ((unsigned int)k < T) {
      nl++;
      sum += fmaxf(Dq - __half2float(__ushort_as_half(k)), 0.f);
    }
  }
  nl = wred_i(nl);
  sum = wred_f(sum);
  if ((tid & 63) == 0) { ish[tid >> 6] = nl; fsh[tid >> 6] = sum; }
  __syncthreads();
  if (tid == 0) {
    int n_less = ish[0] + ish[1] + ish[2] + ish[3];
    float s = fsh[0] + fsh[1] + fsh[2] + fsh[3];
    s += (float)(KNEG - n_less) * fmaxf(Dq - Tval, 0.f);
    atomicAdd(out, s * (1.0f / (2.0f * (float)KNEG * (float)TL)));
  }
}

extern "C" void kernel_launch(void* const* d_in, const int* in_sizes, int n_in,
                              void* d_out, int out_size, void* d_ws, size_t ws_size,
                              hipStream_t stream) {
  const float* emb = (const float*)d_in[0];
  const float* c = (const float*)d_in[1];
  const int* links = (const int*)d_in[2];
  float* out = (float*)d_out;
  float* Dws = (float*)d_ws;  // 3000 floats

  hipMemsetAsync(d_out, 0, sizeof(float), stream);
  d_kernel<<<(TL + 255) / 256, 256, 0, stream>>>(emb, c, links, Dws);
  score_select_kernel<<<NQ, 256, 0, stream>>>(emb, c, links, Dws, out);
}

// Round 2
// 167.504 us; speedup vs baseline: 59.2026x; 59.2026x over previous
//
#include <hip/hip_runtime.h>
#include <hip/hip_fp16.h>
#include <hip/hip_bf16.h>

#define TL 3000
#define NN 30000
#define DIM 128
#define KNEG 75
#define NQ (2 * TL)
#define EPSF 1e-7f
#define MAXSQ 50.0f

#define MT 64        // queries per WG tile
#define NTCH 64      // embedding rows per LDS chunk
#define QROWS 6016   // 6000 padded to 94*64
#define EROWS 30016  // 30000 padded to 469*64
#define NCHUNK 469
#define NSPLIT 8
#define LDQ 136      // padded LDS row length (bf16 elems): +8 breaks bank conflicts
#define MARGIN 50

typedef __attribute__((ext_vector_type(8))) short bf16x8;
typedef __attribute__((ext_vector_type(4))) float f32x4;

__device__ __forceinline__ int wred_i(int v) {
#pragma unroll
  for (int o = 32; o > 0; o >>= 1) v += __shfl_xor(v, o, 64);
  return v;
}
__device__ __forceinline__ float wred_f(float v) {
#pragma unroll
  for (int o = 32; o > 0; o >>= 1) v += __shfl_xor(v, o, 64);
  return v;
}

__device__ __forceinline__ float sqdist_f(float prod, float cv, float K) {
  float theta = fmaxf(-prod * cv, 1.0f + EPSF);
  float a = acoshf(theta);
  return fminf(K * a * a, MAXSQ);
}

__device__ __forceinline__ unsigned short to_bf16(float x) {
  __hip_bfloat16 h = __float2bfloat16(x);
  return *(unsigned short*)&h;
}

// ---------- D for the 3000 links (fp32 exact) ----------
__global__ void d_kernel(const float* __restrict__ emb, const float* __restrict__ c,
                         const int* __restrict__ links, float* __restrict__ D) {
  int i = blockIdx.x * blockDim.x + threadIdx.x;
  if (i >= TL) return;
  long l = links[2 * i];
  long r = links[2 * i + 1];
  const float* x = emb + l * DIM;
  const float* y = emb + r * DIM;
  float dot = 0.f;
  for (int k = 0; k < DIM; ++k) dot = fmaf(x[k], y[k], dot);
  float prod = dot - 2.0f * x[0] * y[0];
  float cv = c[0];
  float K = 1.0f / cv;
  D[i] = sqdist_f(prod, cv, K) + 1.0f;  // + GAMMA
}

// ---------- bf16 conversion of embeddings (row-padded to EROWS, zeros) ----------
__global__ void prep_e(const float* __restrict__ emb, unsigned short* __restrict__ Eb) {
  int idx = blockIdx.x * blockDim.x + threadIdx.x;  // one per 4 elems
  if (idx >= EROWS * (DIM / 4)) return;
  int r = idx >> 5;
  int k4 = (idx & 31) * 4;
  float4 v = make_float4(0.f, 0.f, 0.f, 0.f);
  if (r < NN) v = *(const float4*)(emb + (size_t)r * DIM + k4);
  ushort4 o;
  o.x = to_bf16(v.x); o.y = to_bf16(v.y); o.z = to_bf16(v.z); o.w = to_bf16(v.w);
  *(ushort4*)(Eb + (size_t)r * DIM + k4) = o;
}

// ---------- bf16 query matrix (6000 gathered rows, col0 negated, pad zeros) ----------
__global__ void prep_q(const float* __restrict__ emb, const int* __restrict__ links,
                       unsigned short* __restrict__ Qb) {
  int idx = blockIdx.x * blockDim.x + threadIdx.x;
  if (idx >= QROWS * (DIM / 4)) return;
  int q = idx >> 5;
  int k4 = (idx & 31) * 4;
  float4 v = make_float4(0.f, 0.f, 0.f, 0.f);
  if (q < NQ) {
    int li = (q < TL) ? q : q - TL;
    int node = (q < TL) ? links[2 * li] : links[2 * li + 1];
    v = *(const float4*)(emb + (size_t)node * DIM + k4);
    if (k4 == 0) v.x = -v.x;  // prod = dot(q', e) with q'[0] = -q[0]
  }
  ushort4 o;
  o.x = to_bf16(v.x); o.y = to_bf16(v.y); o.z = to_bf16(v.z); o.w = to_bf16(v.w);
  *(ushort4*)(Qb + (size_t)q * DIM + k4) = o;
}

// ---------- MFMA GEMM + threshold count ----------
// counts[q] += #{ n : dot(q', e_n) >= -(1+eps)/c }   (i.e. theta clipped)
__launch_bounds__(256)
__global__ void gemm_count_kernel(const unsigned short* __restrict__ Qb,
                                  const unsigned short* __restrict__ Eb,
                                  const float* __restrict__ c,
                                  int* __restrict__ counts) {
  __shared__ unsigned short Qs[MT][LDQ];
  __shared__ unsigned short Es[NTCH][LDQ];
  const int tid = threadIdx.x;
  const int qtile = blockIdx.x / NSPLIT;
  const int spl = blockIdx.x % NSPLIT;
  const float thresh = -(1.0f + EPSF) / c[0];

  // stage Q tile (64 x 128 bf16) into padded LDS
  {
    const uint4* src = (const uint4*)(Qb + (size_t)(qtile * MT) * DIM);
#pragma unroll
    for (int i = 0; i < 4; ++i) {
      int u = tid + 256 * i;
      int r = u >> 4, sg = u & 15;
      *(uint4*)&Qs[r][sg * 8] = src[r * 16 + sg];
    }
  }

  const int lane = tid & 63;
  const int wv = tid >> 6;       // wave id: rows wv*16..wv*16+15 of the Q tile
  const int am = lane & 15;
  const int aq = lane >> 4;      // quad
  int cnt0 = 0, cnt1 = 0, cnt2 = 0, cnt3 = 0;

  for (int ch = spl; ch < NCHUNK; ch += NSPLIT) {
    __syncthreads();  // protect Es overwrite (and Q staging on first iter)
    {
      const uint4* src = (const uint4*)(Eb + (size_t)(ch * NTCH) * DIM);
#pragma unroll
      for (int i = 0; i < 4; ++i) {
        int u = tid + 256 * i;
        int r = u >> 4, sg = u & 15;
        *(uint4*)&Es[r][sg * 8] = src[r * 16 + sg];
      }
    }
    __syncthreads();

    // A fragments: A[m=lane&15][k=quad*8+j], m within this wave's 16-row slice
    bf16x8 A0 = *(const bf16x8*)&Qs[wv * 16 + am][0 * 32 + aq * 8];
    bf16x8 A1 = *(const bf16x8*)&Qs[wv * 16 + am][1 * 32 + aq * 8];
    bf16x8 A2 = *(const bf16x8*)&Qs[wv * 16 + am][2 * 32 + aq * 8];
    bf16x8 A3 = *(const bf16x8*)&Qs[wv * 16 + am][3 * 32 + aq * 8];

    const int nb = ch * NTCH;
#pragma unroll
    for (int s = 0; s < 4; ++s) {
      f32x4 acc = {0.f, 0.f, 0.f, 0.f};
      acc = __builtin_amdgcn_mfma_f32_16x16x32_bf16(
          A0, *(const bf16x8*)&Es[s * 16 + am][0 * 32 + aq * 8], acc, 0, 0, 0);
      acc = __builtin_amdgcn_mfma_f32_16x16x32_bf16(
          A1, *(const bf16x8*)&Es[s * 16 + am][1 * 32 + aq * 8], acc, 0, 0, 0);
      acc = __builtin_amdgcn_mfma_f32_16x16x32_bf16(
          A2, *(const bf16x8*)&Es[s * 16 + am][2 * 32 + aq * 8], acc, 0, 0, 0);
      acc = __builtin_amdgcn_mfma_f32_16x16x32_bf16(
          A3, *(const bf16x8*)&Es[s * 16 + am][3 * 32 + aq * 8], acc, 0, 0, 0);
      // D[row][col]: col = lane&15 (the embedding n), row = quad*4+reg (the query m)
      int n = nb + s * 16 + am;
      bool v = (n < NN);
      if (v && acc[0] >= thresh) cnt0++;
      if (v && acc[1] >= thresh) cnt1++;
      if (v && acc[2] >= thresh) cnt2++;
      if (v && acc[3] >= thresh) cnt3++;
    }
  }

  // sum counts over the 16 lanes (low 4 lane bits) sharing the same rows
#pragma unroll
  for (int off = 1; off < 16; off <<= 1) {
    cnt0 += __shfl_xor(cnt0, off, 64);
    cnt1 += __shfl_xor(cnt1, off, 64);
    cnt2 += __shfl_xor(cnt2, off, 64);
    cnt3 += __shfl_xor(cnt3, off, 64);
  }
  if (am == 0) {
    int qb = qtile * MT + wv * 16 + aq * 4;
    atomicAdd(&counts[qb + 0], cnt0);
    atomicAdd(&counts[qb + 1], cnt1);
    atomicAdd(&counts[qb + 2], cnt2);
    atomicAdd(&counts[qb + 3], cnt3);
  }
}

// ---------- finalize: count>=75+margin -> closed-form contribution, else flag ----------
__global__ void finalize_kernel(const int* __restrict__ counts, const float* __restrict__ D,
                                const float* __restrict__ c, int* __restrict__ flags,
                                float* __restrict__ out) {
  __shared__ float fsh[4];
  int q = blockIdx.x * blockDim.x + threadIdx.x;
  float contrib = 0.f;
  if (q < NQ) {
    int li = (q < TL) ? q : q - TL;
    float cv = c[0];
    float K = 1.0f / cv;
    float a = acoshf(1.0f + EPSF);
    float clipv = fminf(K * a * a, MAXSQ);
    if (counts[q] >= KNEG + MARGIN) {
      contrib = (float)KNEG * fmaxf(D[li] - clipv, 0.f);
      flags[q] = 0;
    } else {
      flags[q] = 1;
    }
  }
  float s = wred_f(contrib);
  int tid = threadIdx.x;
  if ((tid & 63) == 0) fsh[tid >> 6] = s;
  __syncthreads();
  if (tid == 0) {
    float t = fsh[0] + fsh[1] + fsh[2] + fsh[3];
    if (t != 0.f)
      atomicAdd(out, t * (1.0f / (2.0f * (float)KNEG * (float)TL)));
  }
}

// ---------- exact fallback (round-0 kernel, flag-gated) ----------
__launch_bounds__(256)
__global__ void score_select_kernel(const float* __restrict__ emb,
                                    const float* __restrict__ c,
                                    const int* __restrict__ links,
                                    const float* __restrict__ D,
                                    const int* __restrict__ flags,
                                    float* __restrict__ out) {
  __shared__ __align__(16) float qvec[DIM];
  __shared__ unsigned short s16[NN];
  __shared__ int ish[4];

  const int q = blockIdx.x;
  if (!flags[q]) return;  // uniform per block
  const int tid = threadIdx.x;
  const int li = (q < TL) ? q : q - TL;
  const int node = (q < TL) ? links[2 * li] : links[2 * li + 1];
  const float Dq = D[li];
  const float cv = c[0];
  const float K = 1.0f / cv;

  if (tid < DIM) qvec[tid] = emb[(long)node * DIM + tid];
  __syncthreads();

  const float q0 = qvec[0];
  const float4* q4 = (const float4*)qvec;

  for (int j = tid; j < NN; j += 256) {
    const float4* row = (const float4*)(emb + (long)j * DIM);
    float acc = 0.f;
    float e0 = 0.f;
#pragma unroll
    for (int k = 0; k < DIM / 4; ++k) {
      float4 e = row[k];
      float4 v = q4[k];
      if (k == 0) e0 = e.x;
      acc = fmaf(e.x, v.x, acc);
      acc = fmaf(e.y, v.y, acc);
      acc = fmaf(e.z, v.z, acc);
      acc = fmaf(e.w, v.w, acc);
    }
    float prod = acc - 2.0f * e0 * q0;
    float s = sqdist_f(prod, cv, K);
    s16[j] = __half_as_ushort(__float2half_rn(s));
  }
  __syncthreads();

  unsigned int lo = 0, hi = 0xFFFFu;
  while (lo < hi) {
    unsigned int mid = (lo + hi) >> 1;
    int cnt = 0;
    for (int j = tid; j < NN; j += 256) cnt += (s16[j] <= mid) ? 1 : 0;
    cnt = wred_i(cnt);
    if ((tid & 63) == 0) ish[tid >> 6] = cnt;
    __syncthreads();
    int tot = ish[0] + ish[1] + ish[2] + ish[3];
    if (tot >= KNEG) hi = mid; else lo = mid + 1;
    __syncthreads();
  }
  const unsigned int T = lo;
  const float Tval = __half2float(__ushort_as_half((unsigned short)T));

  __shared__ float fsh[4];
  int nl = 0;
  float sum = 0.f;
  for (int j = tid; j < NN; j += 256) {
    unsigned short k = s16[j];
    if ((unsigned int)k < T) {
      nl++;
      sum += fmaxf(Dq - __half2float(__ushort_as_half(k)), 0.f);
    }
  }
  nl = wred_i(nl);
  sum = wred_f(sum);
  if ((tid & 63) == 0) { ish[tid >> 6] = nl; fsh[tid >> 6] = sum; }
  __syncthreads();
  if (tid == 0) {
    int n_less = ish[0] + ish[1] + ish[2] + ish[3];
    float s = fsh[0] + fsh[1] + fsh[2] + fsh[3];
    s += (float)(KNEG - n_less) * fmaxf(Dq - Tval, 0.f);
    atomicAdd(out, s * (1.0f / (2.0f * (float)KNEG * (float)TL)));
  }
}

extern "C" void kernel_launch(void* const* d_in, const int* in_sizes, int n_in,
                              void* d_out, int out_size, void* d_ws, size_t ws_size,
                              hipStream_t stream) {
  const float* emb = (const float*)d_in[0];
  const float* c = (const float*)d_in[1];
  const int* links = (const int*)d_in[2];
  float* out = (float*)d_out;

  // workspace layout (bytes): Eb 7,684,096 | Qb 1,540,096 | counts 24,064 | D 12,000 | flags 24,000
  unsigned short* Eb = (unsigned short*)d_ws;
  unsigned short* Qb = Eb + (size_t)EROWS * DIM;
  int* counts = (int*)(Qb + (size_t)QROWS * DIM);
  float* Dws = (float*)(counts + QROWS);
  int* flags = (int*)(Dws + TL);

  hipMemsetAsync(d_out, 0, sizeof(float), stream);
  hipMemsetAsync(counts, 0, QROWS * sizeof(int), stream);

  prep_e<<<(EROWS * (DIM / 4) + 255) / 256, 256, 0, stream>>>(emb, Eb);
  prep_q<<<(QROWS * (DIM / 4) + 255) / 256, 256, 0, stream>>>(emb, links, Qb);
  d_kernel<<<(TL + 255) / 256, 256, 0, stream>>>(emb, c, links, Dws);
  gemm_count_kernel<<<(QROWS / MT) * NSPLIT, 256, 0, stream>>>(Qb, Eb, c, counts);
  finalize_kernel<<<(NQ + 255) / 256, 256, 0, stream>>>(counts, Dws, c, flags, out);
  score_select_kernel<<<NQ, 256, 0, stream>>>(emb, c, links, Dws, flags, out);
}

// Round 3
// 129.269 us; speedup vs baseline: 76.7132x; 1.2958x over previous
//
#include <hip/hip_runtime.h>
#include <hip/hip_fp16.h>
#include <hip/hip_bf16.h>

#define TL 3000
#define NN 30000
#define DIM 128
#define KNEG 75
#define NQL (2 * TL)
#define EPSF 1e-7f
#define MAXSQ 50.0f

#define MT 256        // queries per WG (4 waves x 64 rows)
#define QROWS 6144    // 24 * 256
#define EROWS 30016   // 469 * 64
#define NCHUNK 469
#define NSPLIT 32     // 24*32 = 768 blocks = 3/CU
#define MARGIN 50

typedef __attribute__((ext_vector_type(8))) short bf16x8;
typedef __attribute__((ext_vector_type(4))) float f32x4;

__device__ __forceinline__ int wred_i(int v) {
#pragma unroll
  for (int o = 32; o > 0; o >>= 1) v += __shfl_xor(v, o, 64);
  return v;
}
__device__ __forceinline__ float wred_f(float v) {
#pragma unroll
  for (int o = 32; o > 0; o >>= 1) v += __shfl_xor(v, o, 64);
  return v;
}

__device__ __forceinline__ float sqdist_f(float prod, float cv, float K) {
  float theta = fmaxf(-prod * cv, 1.0f + EPSF);
  float a = acoshf(theta);
  return fminf(K * a * a, MAXSQ);
}

__device__ __forceinline__ unsigned short to_bf16(float x) {
  __hip_bfloat16 h = __float2bfloat16(x);
  return *(unsigned short*)&h;
}

// async 16B global->LDS DMA: LDS dest = uniform base + lane*16
__device__ __forceinline__ void gload16(const unsigned short* g, unsigned short* l) {
  __builtin_amdgcn_global_load_lds((const __attribute__((address_space(1))) void*)g,
                                   (__attribute__((address_space(3))) void*)l, 16, 0, 0);
}

// ---------- fused prep: Eb bf16 | Qb bf16 (gathered, col0 negated) | D | zero counts/out ----------
__global__ void prep_all(const float* __restrict__ emb, const float* __restrict__ c,
                         const int* __restrict__ links, unsigned short* __restrict__ Eb,
                         unsigned short* __restrict__ Qb, float* __restrict__ D,
                         int* __restrict__ counts, float* __restrict__ out) {
  int idx = blockIdx.x * 256 + threadIdx.x;
  const int NE = EROWS * 32;
  const int NQ4 = QROWS * 32;
  if (idx < NE) {
    int r = idx >> 5, k4 = (idx & 31) * 4;
    float4 v = make_float4(0.f, 0.f, 0.f, 0.f);
    if (r < NN) v = *(const float4*)(emb + (size_t)r * DIM + k4);
    ushort4 o;
    o.x = to_bf16(v.x); o.y = to_bf16(v.y); o.z = to_bf16(v.z); o.w = to_bf16(v.w);
    *(ushort4*)(Eb + (size_t)r * DIM + k4) = o;
    return;
  }
  idx -= NE;
  if (idx < NQ4) {
    int q = idx >> 5, k4 = (idx & 31) * 4;
    float4 v = make_float4(0.f, 0.f, 0.f, 0.f);
    if (q < NQL) {
      int li = (q < TL) ? q : q - TL;
      int node = (q < TL) ? links[2 * li] : links[2 * li + 1];
      v = *(const float4*)(emb + (size_t)node * DIM + k4);
      if (k4 == 0) v.x = -v.x;  // prod = dot(q', e), q'[0] = -q[0]
    }
    ushort4 o;
    o.x = to_bf16(v.x); o.y = to_bf16(v.y); o.z = to_bf16(v.z); o.w = to_bf16(v.w);
    *(ushort4*)(Qb + (size_t)q * DIM + k4) = o;
    return;
  }
  idx -= NQ4;
  if (idx < TL) {
    long l = links[2 * idx];
    long r = links[2 * idx + 1];
    const float* x = emb + l * DIM;
    const float* y = emb + r * DIM;
    float dot = 0.f;
    for (int k = 0; k < DIM; ++k) dot = fmaf(x[k], y[k], dot);
    float prod = dot - 2.0f * x[0] * y[0];
    float cv = c[0];
    D[idx] = sqdist_f(prod, cv, 1.0f / cv) + 1.0f;  // + GAMMA
    return;
  }
  idx -= TL;
  if (idx < QROWS) { counts[idx] = 0; return; }
  idx -= QROWS;
  if (idx == 0) out[0] = 0.f;
}

// ---------- MFMA GEMM + threshold count ----------
// counts[q] += #{ n : dot(q', e_n) >= -(1+eps)/c }
// LDS holds E-chunks in MFMA-B-fragment order: slot (s*4+kc)*64 + lane  (16B each)
//  = E[row ch*64 + s*16 + (lane&15)][k = kc*32 + (lane>>4)*8 .. +8]
__launch_bounds__(256)
__global__ void gemm_count_kernel(const unsigned short* __restrict__ Qb,
                                  const unsigned short* __restrict__ Eb,
                                  const float* __restrict__ c,
                                  int* __restrict__ counts) {
  __shared__ __align__(16) unsigned short Es[2][64 * DIM];  // 2 x 16 KB
  const int tid = threadIdx.x;
  const int lane = tid & 63;
  const int w = tid >> 6;
  const int am = lane & 15;
  const int aq = lane >> 4;
  const int qt = blockIdx.x / NSPLIT;
  const int spl = blockIdx.x % NSPLIT;
  const float thresh = -(1.0f + EPSF) / c[0];

  // A fragments for this wave's 64 query rows, whole K=128, held in VGPRs.
  bf16x8 A[4][4];
  {
    const unsigned short* qb = Qb + (size_t)(qt * MT + w * 64) * DIM;
#pragma unroll
    for (int mg = 0; mg < 4; ++mg)
#pragma unroll
      for (int kc = 0; kc < 4; ++kc)
        A[mg][kc] = *(const bf16x8*)(qb + (mg * 16 + am) * DIM + kc * 32 + aq * 8);
  }

  int cnt[4][4];
#pragma unroll
  for (int mg = 0; mg < 4; ++mg)
#pragma unroll
    for (int r = 0; r < 4; ++r) cnt[mg][r] = 0;

  const int grow = w * 16 + am;  // staged row within chunk (wave w stages s-group w)
  const int gcol = aq * 8;       // shorts; + i*32 per instruction

  int ch = spl;
  {  // prologue: stage chunk ch into buf 0
    const unsigned short* g = Eb + (size_t)(ch * 64 + grow) * DIM + gcol;
    unsigned short* lb = &Es[0][w * 4 * 512];
#pragma unroll
    for (int i = 0; i < 4; ++i) gload16(g + i * 32, lb + i * 512);
  }
  int buf = 0;
  while (ch < NCHUNK) {
    __syncthreads();  // drains vmcnt -> buf ready; prev compute done -> buf^1 writable
    int nxt = ch + NSPLIT;
    if (nxt < NCHUNK) {
      const unsigned short* g = Eb + (size_t)(nxt * 64 + grow) * DIM + gcol;
      unsigned short* lb = &Es[buf ^ 1][w * 4 * 512];
#pragma unroll
      for (int i = 0; i < 4; ++i) gload16(g + i * 32, lb + i * 512);
    }
    const unsigned short* eb = &Es[buf][0];
#pragma unroll
    for (int s = 0; s < 4; ++s) {
      f32x4 a0 = {0.f, 0.f, 0.f, 0.f}, a1 = {0.f, 0.f, 0.f, 0.f};
      f32x4 a2 = {0.f, 0.f, 0.f, 0.f}, a3 = {0.f, 0.f, 0.f, 0.f};
#pragma unroll
      for (int kc = 0; kc < 4; ++kc) {
        bf16x8 B = *(const bf16x8*)(eb + ((s * 4 + kc) * 64 + lane) * 8);
        a0 = __builtin_amdgcn_mfma_f32_16x16x32_bf16(A[0][kc], B, a0, 0, 0, 0);
        a1 = __builtin_amdgcn_mfma_f32_16x16x32_bf16(A[1][kc], B, a1, 0, 0, 0);
        a2 = __builtin_amdgcn_mfma_f32_16x16x32_bf16(A[2][kc], B, a2, 0, 0, 0);
        a3 = __builtin_amdgcn_mfma_f32_16x16x32_bf16(A[3][kc], B, a3, 0, 0, 0);
      }
      int v = (ch * 64 + s * 16 + am) < NN;  // n = col = lane&15 (+pad guard)
#pragma unroll
      for (int r = 0; r < 4; ++r) {
        cnt[0][r] += v & (a0[r] >= thresh);
        cnt[1][r] += v & (a1[r] >= thresh);
        cnt[2][r] += v & (a2[r] >= thresh);
        cnt[3][r] += v & (a3[r] >= thresh);
      }
    }
    buf ^= 1;
    ch = nxt;
  }

  // reduce over the 16 n-lanes (low 4 lane bits); row m = mg*16 + aq*4 + r
#pragma unroll
  for (int mg = 0; mg < 4; ++mg)
#pragma unroll
    for (int r = 0; r < 4; ++r) {
      int v = cnt[mg][r];
      v += __shfl_xor(v, 1, 64);
      v += __shfl_xor(v, 2, 64);
      v += __shfl_xor(v, 4, 64);
      v += __shfl_xor(v, 8, 64);
      if (am == 0) atomicAdd(&counts[qt * MT + w * 64 + mg * 16 + aq * 4 + r], v);
    }
}

// ---------- finalize: count>=75+margin -> closed-form contribution, else flag ----------
__global__ void finalize_kernel(const int* __restrict__ counts, const float* __restrict__ D,
                                const float* __restrict__ c, int* __restrict__ flags,
                                float* __restrict__ out) {
  __shared__ float fsh[4];
  int q = blockIdx.x * blockDim.x + threadIdx.x;
  float contrib = 0.f;
  if (q < NQL) {
    int li = (q < TL) ? q : q - TL;
    float cv = c[0];
    float K = 1.0f / cv;
    float a = acoshf(1.0f + EPSF);
    float clipv = fminf(K * a * a, MAXSQ);
    if (counts[q] >= KNEG + MARGIN) {
      contrib = (float)KNEG * fmaxf(D[li] - clipv, 0.f);
      flags[q] = 0;
    } else {
      flags[q] = 1;
    }
  }
  float s = wred_f(contrib);
  int tid = threadIdx.x;
  if ((tid & 63) == 0) fsh[tid >> 6] = s;
  __syncthreads();
  if (tid == 0) {
    float t = fsh[0] + fsh[1] + fsh[2] + fsh[3];
    if (t != 0.f) atomicAdd(out, t * (1.0f / (2.0f * (float)KNEG * (float)TL)));
  }
}

// ---------- exact fallback (flag-gated; statistically never taken) ----------
__launch_bounds__(256)
__global__ void score_select_kernel(const float* __restrict__ emb,
                                    const float* __restrict__ c,
                                    const int* __restrict__ links,
                                    const float* __restrict__ D,
                                    const int* __restrict__ flags,
                                    float* __restrict__ out) {
  __shared__ __align__(16) float qvec[DIM];
  __shared__ unsigned short s16[NN];
  __shared__ int ish[4];

  const int q = blockIdx.x;
  if (!flags[q]) return;
  const int tid = threadIdx.x;
  const int li = (q < TL) ? q : q - TL;
  const int node = (q < TL) ? links[2 * li] : links[2 * li + 1];
  const float Dq = D[li];
  const float cv = c[0];
  const float K = 1.0f / cv;

  if (tid < DIM) qvec[tid] = emb[(long)node * DIM + tid];
  __syncthreads();

  const float q0 = qvec[0];
  const float4* q4 = (const float4*)qvec;

  for (int j = tid; j < NN; j += 256) {
    const float4* row = (const float4*)(emb + (long)j * DIM);
    float acc = 0.f;
    float e0 = 0.f;
#pragma unroll
    for (int k = 0; k < DIM / 4; ++k) {
      float4 e = row[k];
      float4 v = q4[k];
      if (k == 0) e0 = e.x;
      acc = fmaf(e.x, v.x, acc);
      acc = fmaf(e.y, v.y, acc);
      acc = fmaf(e.z, v.z, acc);
      acc = fmaf(e.w, v.w, acc);
    }
    float prod = acc - 2.0f * e0 * q0;
    float s = sqdist_f(prod, cv, K);
    s16[j] = __half_as_ushort(__float2half_rn(s));
  }
  __syncthreads();

  unsigned int lo = 0, hi = 0xFFFFu;
  while (lo < hi) {
    unsigned int mid = (lo + hi) >> 1;
    int cnt = 0;
    for (int j = tid; j < NN; j += 256) cnt += (s16[j] <= mid) ? 1 : 0;
    cnt = wred_i(cnt);
    if ((tid & 63) == 0) ish[tid >> 6] = cnt;
    __syncthreads();
    int tot = ish[0] + ish[1] + ish[2] + ish[3];
    if (tot >= KNEG) hi = mid; else lo = mid + 1;
    __syncthreads();
  }
  const unsigned int T = lo;
  const float Tval = __half2float(__ushort_as_half((unsigned short)T));

  __shared__ float fsh[4];
  int nl = 0;
  float sum = 0.f;
  for (int j = tid; j < NN; j += 256) {
    unsigned short k = s16[j];
    if ((unsigned int)k < T) {
      nl++;
      sum += fmaxf(Dq - __half2float(__ushort_as_half(k)), 0.f);
    }
  }
  nl = wred_i(nl);
  sum = wred_f(sum);
  if ((tid & 63) == 0) { ish[tid >> 6] = nl; fsh[tid >> 6] = sum; }
  __syncthreads();
  if (tid == 0) {
    int n_less = ish[0] + ish[1] + ish[2] + ish[3];
    float s = fsh[0] + fsh[1] + fsh[2] + fsh[3];
    s += (float)(KNEG - n_less) * fmaxf(Dq - Tval, 0.f);
    atomicAdd(out, s * (1.0f / (2.0f * (float)KNEG * (float)TL)));
  }
}

extern "C" void kernel_launch(void* const* d_in, const int* in_sizes, int n_in,
                              void* d_out, int out_size, void* d_ws, size_t ws_size,
                              hipStream_t stream) {
  const float* emb = (const float*)d_in[0];
  const float* c = (const float*)d_in[1];
  const int* links = (const int*)d_in[2];
  float* out = (float*)d_out;

  unsigned short* Eb = (unsigned short*)d_ws;             // 7,684,096 B
  unsigned short* Qb = Eb + (size_t)EROWS * DIM;          // 1,572,864 B
  int* counts = (int*)(Qb + (size_t)QROWS * DIM);         // 24,576 B
  float* Dws = (float*)(counts + QROWS);                  // 12,000 B
  int* flags = (int*)(Dws + TL);                          // 24,000 B

  const int prep_items = EROWS * 32 + QROWS * 32 + TL + QROWS + 1;
  prep_all<<<(prep_items + 255) / 256, 256, 0, stream>>>(emb, c, links, Eb, Qb, Dws,
                                                         counts, out);
  gemm_count_kernel<<<(QROWS / MT) * NSPLIT, 256, 0, stream>>>(Qb, Eb, c, counts);
  finalize_kernel<<<(NQL + 255) / 256, 256, 0, stream>>>(counts, Dws, c, flags, out);
  score_select_kernel<<<NQL, 256, 0, stream>>>(emb, c, links, Dws, flags, out);
}

// Round 4
// 101.543 us; speedup vs baseline: 97.6597x; 1.2730x over previous
//
#include <hip/hip_runtime.h>
#include <hip/hip_fp16.h>
#include <hip/hip_bf16.h>

#define TL 3000
#define NN 30000
#define DIM 128
#define KNEG 75
#define NQL (2 * TL)
#define EPSF 1e-7f
#define MAXSQ 50.0f

#define ESUB 2048        // candidate subsample for the count gate
#define ECH 128          // candidate rows per LDS chunk
#define NCH (ESUB / ECH) // 16
#define QT 64            // query rows per block
#define QBLK 94          // ceil(6000/64)
#define FLAGTH (KNEG + 50)

typedef __attribute__((ext_vector_type(8))) short bf16x8;
typedef __attribute__((ext_vector_type(4))) float f32x4;

__device__ __forceinline__ int wred_i(int v) {
#pragma unroll
  for (int o = 32; o > 0; o >>= 1) v += __shfl_xor(v, o, 64);
  return v;
}
__device__ __forceinline__ float wred_f(float v) {
#pragma unroll
  for (int o = 32; o > 0; o >>= 1) v += __shfl_xor(v, o, 64);
  return v;
}

__device__ __forceinline__ float sqdist_f(float prod, float cv, float K) {
  float theta = fmaxf(-prod * cv, 1.0f + EPSF);
  float a = acoshf(theta);
  return fminf(K * a * a, MAXSQ);
}

__device__ __forceinline__ unsigned short to_bf16(float x) {
  __hip_bfloat16 h = __float2bfloat16(x);
  return *(unsigned short*)&h;
}

__device__ __forceinline__ void gload16(const unsigned short* g, unsigned short* l) {
  __builtin_amdgcn_global_load_lds((const __attribute__((address_space(1))) void*)g,
                                   (__attribute__((address_space(3))) void*)l, 16, 0, 0);
}

// ---------- prep: Eb bf16 (first ESUB rows) | D | zero nflag/out ----------
__global__ void prep(const float* __restrict__ emb, const float* __restrict__ c,
                     const int* __restrict__ links, unsigned short* __restrict__ Eb,
                     float* __restrict__ D, int* __restrict__ nflag,
                     float* __restrict__ out) {
  int idx = blockIdx.x * 256 + threadIdx.x;
  const int NE = ESUB * 32;
  if (idx < NE) {
    int r = idx >> 5, k4 = (idx & 31) * 4;
    float4 v = *(const float4*)(emb + (size_t)r * DIM + k4);
    ushort4 o;
    o.x = to_bf16(v.x); o.y = to_bf16(v.y); o.z = to_bf16(v.z); o.w = to_bf16(v.w);
    *(ushort4*)(Eb + (size_t)r * DIM + k4) = o;
    return;
  }
  idx -= NE;
  if (idx < TL) {
    long l = links[2 * idx];
    long r = links[2 * idx + 1];
    const float4* x = (const float4*)(emb + l * DIM);
    const float4* y = (const float4*)(emb + r * DIM);
    float dot = 0.f;
    float x0 = 0.f, y0 = 0.f;
#pragma unroll
    for (int k = 0; k < 32; ++k) {
      float4 a = x[k], b = y[k];
      if (k == 0) { x0 = a.x; y0 = b.x; }
      dot = fmaf(a.x, b.x, dot);
      dot = fmaf(a.y, b.y, dot);
      dot = fmaf(a.z, b.z, dot);
      dot = fmaf(a.w, b.w, dot);
    }
    float prod = dot - 2.0f * x0 * y0;
    float cv = c[0];
    D[idx] = sqdist_f(prod, cv, 1.0f / cv) + 1.0f;  // + GAMMA
    return;
  }
  idx -= TL;
  if (idx == 0) { *nflag = 0; *out = 0.f; }
}

// ---------- fused: MFMA count over ESUB candidates + finalize ----------
// Block qt owns query rows qt*64..+63. Waves split candidate s-groups.
__launch_bounds__(256)
__global__ void gemm_cf(const float* __restrict__ emb, const float* __restrict__ c,
                        const int* __restrict__ links, const unsigned short* __restrict__ Eb,
                        const float* __restrict__ D, int* __restrict__ nflag,
                        int* __restrict__ list, float* __restrict__ out) {
  __shared__ __align__(16) unsigned short Es[2][ECH * DIM];  // 2 x 32 KB = 64 KB
  const int tid = threadIdx.x;
  const int lane = tid & 63;
  const int w = tid >> 6;
  const int am = lane & 15;
  const int aq = lane >> 4;
  const int qt = blockIdx.x;
  const float cv = c[0];
  const float thresh = -(1.0f + EPSF) / cv;

  // A fragments: gather this block's 64 query rows from emb (fp32), convert bf16.
  // A[m=lane&15][k=quad*8+j]; col0 negated so prod = dot(q', e).
  bf16x8 A[4][4];
#pragma unroll
  for (int mg = 0; mg < 4; ++mg) {
    int q = qt * QT + mg * 16 + am;
    int node = 0;
    if (q < NQL) {
      int li = (q < TL) ? q : q - TL;
      node = (q < TL) ? links[2 * li] : links[2 * li + 1];
    }
    const float* qr = emb + (size_t)node * DIM;
#pragma unroll
    for (int kc = 0; kc < 4; ++kc) {
      float4 f0 = *(const float4*)(qr + kc * 32 + aq * 8);
      float4 f1 = *(const float4*)(qr + kc * 32 + aq * 8 + 4);
      if (kc == 0 && aq == 0) f0.x = -f0.x;
      bf16x8 v;
      v[0] = (short)to_bf16(f0.x); v[1] = (short)to_bf16(f0.y);
      v[2] = (short)to_bf16(f0.z); v[3] = (short)to_bf16(f0.w);
      v[4] = (short)to_bf16(f1.x); v[5] = (short)to_bf16(f1.y);
      v[6] = (short)to_bf16(f1.z); v[7] = (short)to_bf16(f1.w);
      A[mg][kc] = v;
    }
  }

  int cnt[4][4];
#pragma unroll
  for (int mg = 0; mg < 4; ++mg)
#pragma unroll
    for (int r = 0; r < 4; ++r) cnt[mg][r] = 0;

  // staging: thread's 8 DMA instrs cover slot-groups g = w*8+i (sg = g>>2, kc = g&3)
  // slot (sg*4+kc)*64 + lane holds E[ch*ECH + sg*16 + am][kc*32 + aq*8 ..+8]
#define STAGE(CH, B)                                                                   \
  {                                                                                    \
    _Pragma("unroll") for (int i = 0; i < 8; ++i) {                                    \
      int g = w * 8 + i;                                                               \
      int sg = g >> 2, kc = g & 3;                                                     \
      const unsigned short* src =                                                      \
          Eb + (size_t)((CH) * ECH + sg * 16 + am) * DIM + kc * 32 + aq * 8;           \
      gload16(src, &Es[(B)][g * 64 * 8]);                                              \
    }                                                                                  \
  }

  STAGE(0, 0);
  int buf = 0;
  for (int ch = 0; ch < NCH; ++ch) {
    __syncthreads();  // drains vmcnt: buf ready; prior compute done: buf^1 writable
    if (ch + 1 < NCH) STAGE(ch + 1, buf ^ 1);
#pragma unroll
    for (int s2 = 0; s2 < 2; ++s2) {
      int sg = w + s2 * 4;
      f32x4 a0 = {0.f, 0.f, 0.f, 0.f}, a1 = {0.f, 0.f, 0.f, 0.f};
      f32x4 a2 = {0.f, 0.f, 0.f, 0.f}, a3 = {0.f, 0.f, 0.f, 0.f};
#pragma unroll
      for (int kc = 0; kc < 4; ++kc) {
        bf16x8 B = *(const bf16x8*)&Es[buf][((sg * 4 + kc) * 64 + lane) * 8];
        a0 = __builtin_amdgcn_mfma_f32_16x16x32_bf16(A[0][kc], B, a0, 0, 0, 0);
        a1 = __builtin_amdgcn_mfma_f32_16x16x32_bf16(A[1][kc], B, a1, 0, 0, 0);
        a2 = __builtin_amdgcn_mfma_f32_16x16x32_bf16(A[2][kc], B, a2, 0, 0, 0);
        a3 = __builtin_amdgcn_mfma_f32_16x16x32_bf16(A[3][kc], B, a3, 0, 0, 0);
      }
#pragma unroll
      for (int r = 0; r < 4; ++r) {
        cnt[0][r] += (a0[r] >= thresh);
        cnt[1][r] += (a1[r] >= thresh);
        cnt[2][r] += (a2[r] >= thresh);
        cnt[3][r] += (a3[r] >= thresh);
      }
    }
    buf ^= 1;
  }

  // cross-wave count reduction in LDS (reuse Es), then finalize in-block
  __syncthreads();
  int* lcnt = (int*)&Es[0][0];
  if (tid < QT) lcnt[tid] = 0;
  __syncthreads();
#pragma unroll
  for (int mg = 0; mg < 4; ++mg)
#pragma unroll
    for (int r = 0; r < 4; ++r) {
      int v = cnt[mg][r];
      v += __shfl_xor(v, 1, 64);
      v += __shfl_xor(v, 2, 64);
      v += __shfl_xor(v, 4, 64);
      v += __shfl_xor(v, 8, 64);
      if (am == 0) atomicAdd(&lcnt[mg * 16 + aq * 4 + r], v);
    }
  __syncthreads();
  if (tid < QT) {
    int q = qt * QT + tid;
    float contrib = 0.f;
    if (q < NQL) {
      int li = (q < TL) ? q : q - TL;
      float K = 1.0f / cv;
      float a = acoshf(1.0f + EPSF);
      float clipv = fminf(K * a * a, MAXSQ);
      if (lcnt[tid] >= FLAGTH) {
        contrib = (float)KNEG * fmaxf(D[li] - clipv, 0.f);
      } else {
        int p = atomicAdd(nflag, 1);
        list[p] = q;
      }
    }
    contrib = wred_f(contrib);
    if (tid == 0 && contrib != 0.f)
      atomicAdd(out, contrib * (1.0f / (2.0f * (float)KNEG * (float)TL)));
  }
}

// ---------- exact fallback over the flagged list (normally empty) ----------
__launch_bounds__(256)
__global__ void fallback_kernel(const float* __restrict__ emb, const float* __restrict__ c,
                                const int* __restrict__ links, const float* __restrict__ D,
                                const int* __restrict__ nflag, const int* __restrict__ list,
                                float* __restrict__ out) {
  __shared__ __align__(16) float qvec[DIM];
  __shared__ unsigned short s16[NN];
  __shared__ int ish[4];
  __shared__ float fsh[4];
  const int tid = threadIdx.x;
  const int nf = *nflag;

  for (int it = blockIdx.x; it < nf; it += gridDim.x) {
    const int q = list[it];
    const int li = (q < TL) ? q : q - TL;
    const int node = (q < TL) ? links[2 * li] : links[2 * li + 1];
    const float Dq = D[li];
    const float cv = c[0];
    const float K = 1.0f / cv;

    if (tid < DIM) qvec[tid] = emb[(long)node * DIM + tid];
    __syncthreads();

    const float q0 = qvec[0];
    const float4* q4 = (const float4*)qvec;

    for (int j = tid; j < NN; j += 256) {
      const float4* row = (const float4*)(emb + (long)j * DIM);
      float acc = 0.f;
      float e0 = 0.f;
#pragma unroll
      for (int k = 0; k < DIM / 4; ++k) {
        float4 e = row[k];
        float4 v = q4[k];
        if (k == 0) e0 = e.x;
        acc = fmaf(e.x, v.x, acc);
        acc = fmaf(e.y, v.y, acc);
        acc = fmaf(e.z, v.z, acc);
        acc = fmaf(e.w, v.w, acc);
      }
      float prod = acc - 2.0f * e0 * q0;
      float s = sqdist_f(prod, cv, K);
      s16[j] = __half_as_ushort(__float2half_rn(s));
    }
    __syncthreads();

    unsigned int lo = 0, hi = 0xFFFFu;
    while (lo < hi) {
      unsigned int mid = (lo + hi) >> 1;
      int cnt = 0;
      for (int j = tid; j < NN; j += 256) cnt += (s16[j] <= mid) ? 1 : 0;
      cnt = wred_i(cnt);
      if ((tid & 63) == 0) ish[tid >> 6] = cnt;
      __syncthreads();
      int tot = ish[0] + ish[1] + ish[2] + ish[3];
      if (tot >= KNEG) hi = mid; else lo = mid + 1;
      __syncthreads();
    }
    const unsigned int T = lo;
    const float Tval = __half2float(__ushort_as_half((unsigned short)T));

    int nl = 0;
    float sum = 0.f;
    for (int j = tid; j < NN; j += 256) {
      unsigned short k = s16[j];
      if ((unsigned int)k < T) {
        nl++;
        sum += fmaxf(Dq - __half2float(__ushort_as_half(k)), 0.f);
      }
    }
    nl = wred_i(nl);
    sum = wred_f(sum);
    if ((tid & 63) == 0) { ish[tid >> 6] = nl; fsh[tid >> 6] = sum; }
    __syncthreads();
    if (tid == 0) {
      int n_less = ish[0] + ish[1] + ish[2] + ish[3];
      float s = fsh[0] + fsh[1] + fsh[2] + fsh[3];
      s += (float)(KNEG - n_less) * fmaxf(Dq - Tval, 0.f);
      atomicAdd(out, s * (1.0f / (2.0f * (float)KNEG * (float)TL)));
    }
    __syncthreads();
  }
}

extern "C" void kernel_launch(void* const* d_in, const int* in_sizes, int n_in,
                              void* d_out, int out_size, void* d_ws, size_t ws_size,
                              hipStream_t stream) {
  const float* emb = (const float*)d_in[0];
  const float* c = (const float*)d_in[1];
  const int* links = (const int*)d_in[2];
  float* out = (float*)d_out;

  unsigned short* Eb = (unsigned short*)d_ws;      // 524,288 B
  float* Dws = (float*)(Eb + (size_t)ESUB * DIM);  // 12,000 B
  int* list = (int*)(Dws + TL);                    // 24,064 B
  int* nflag = list + QBLK * QT;                   // 4 B

  const int prep_items = ESUB * 32 + TL + 1;
  prep<<<(prep_items + 255) / 256, 256, 0, stream>>>(emb, c, links, Eb, Dws, nflag, out);
  gemm_cf<<<QBLK, 256, 0, stream>>>(emb, c, links, Eb, Dws, nflag, list, out);
  fallback_kernel<<<256, 256, 0, stream>>>(emb, c, links, Dws, nflag, list, out);
}

// Round 5
// 93.239 us; speedup vs baseline: 106.3569x; 1.0891x over previous
//
#include <hip/hip_runtime.h>
#include <hip/hip_fp16.h>
#include <hip/hip_bf16.h>

#define TL 3000
#define NN 30000
#define DIM 128
#define KNEG 75
#define NQL (2 * TL)
#define EPSF 1e-7f
#define MAXSQ 50.0f

#define ESUB 512          // candidate subsample for the count gate
#define ECH 256           // candidate rows per LDS chunk (64 KB)
#define NCH (ESUB / ECH)  // 2
#define QT 64             // query rows per block
#define QBLK 94           // ceil(6000/64)
#define FLAGTH 125        // KNEG + 50 margin

typedef __attribute__((ext_vector_type(8))) short bf16x8;
typedef __attribute__((ext_vector_type(4))) float f32x4;

__device__ __forceinline__ int wred_i(int v) {
#pragma unroll
  for (int o = 32; o > 0; o >>= 1) v += __shfl_xor(v, o, 64);
  return v;
}
__device__ __forceinline__ float wred_f(float v) {
#pragma unroll
  for (int o = 32; o > 0; o >>= 1) v += __shfl_xor(v, o, 64);
  return v;
}

__device__ __forceinline__ float sqdist_f(float prod, float cv, float K) {
  float theta = fmaxf(-prod * cv, 1.0f + EPSF);
  float a = acoshf(theta);
  return fminf(K * a * a, MAXSQ);
}

__device__ __forceinline__ unsigned short to_bf16(float x) {
  __hip_bfloat16 h = __float2bfloat16(x);
  return *(unsigned short*)&h;
}

// ---------- single fused kernel: stage+convert E, MFMA count, D, finalize ----------
// Block qt owns query rows qt*64..+63. partial[qt], nf[qt], list segment written
// unconditionally (no zero-init of workspace needed anywhere).
__launch_bounds__(256)
__global__ void gemm_cf(const float* __restrict__ emb, const float* __restrict__ c,
                        const int* __restrict__ links, float* __restrict__ partial,
                        int* __restrict__ nf, int* __restrict__ list) {
  __shared__ __align__(16) unsigned short Es[ECH * DIM];  // 64 KB
  const int tid = threadIdx.x;
  const int lane = tid & 63;
  const int w = tid >> 6;
  const int am = lane & 15;
  const int aq = lane >> 4;
  const int qt = blockIdx.x;
  const float cv = c[0];
  const float K = 1.0f / cv;
  const float thresh = -(1.0f + EPSF) / cv;

  // A fragments: gather this block's 64 query rows from emb (fp32), convert bf16.
  // A[m=lane&15][k_global = kc*32 + aq*8 + j]; k_global==0 negated (q'[0] = -q[0]).
  bf16x8 A[4][4];
#pragma unroll
  for (int mg = 0; mg < 4; ++mg) {
    int q = qt * QT + mg * 16 + am;
    int node = 0;
    if (q < NQL) {
      int li = (q < TL) ? q : q - TL;
      node = (q < TL) ? links[2 * li] : links[2 * li + 1];
    }
    const float* qr = emb + (size_t)node * DIM;
#pragma unroll
    for (int kc = 0; kc < 4; ++kc) {
      float4 f0 = *(const float4*)(qr + kc * 32 + aq * 8);
      float4 f1 = *(const float4*)(qr + kc * 32 + aq * 8 + 4);
      if (kc == 0 && aq == 0) f0.x = -f0.x;
      bf16x8 v;
      v[0] = (short)to_bf16(f0.x); v[1] = (short)to_bf16(f0.y);
      v[2] = (short)to_bf16(f0.z); v[3] = (short)to_bf16(f0.w);
      v[4] = (short)to_bf16(f1.x); v[5] = (short)to_bf16(f1.y);
      v[6] = (short)to_bf16(f1.z); v[7] = (short)to_bf16(f1.w);
      A[mg][kc] = v;
    }
  }

  int cnt[4][4];
#pragma unroll
  for (int mg = 0; mg < 4; ++mg)
#pragma unroll
    for (int r = 0; r < 4; ++r) cnt[mg][r] = 0;

  // 2 chunks, single-buffered: stage (fp32 load -> bf16 -> LDS in B-frag order),
  // barrier, MFMA, barrier.
  for (int ch = 0; ch < NCH; ++ch) {
#pragma unroll
    for (int i = 0; i < 16; ++i) {
      int g = w * 16 + i;       // slot-group 0..63: sg = g>>2, kc = g&3
      int sg = g >> 2, kc = g & 3;
      const float* src = emb + (size_t)(ch * ECH + sg * 16 + am) * DIM + kc * 32 + aq * 8;
      float4 f0 = *(const float4*)src;
      float4 f1 = *(const float4*)(src + 4);
      bf16x8 v;
      v[0] = (short)to_bf16(f0.x); v[1] = (short)to_bf16(f0.y);
      v[2] = (short)to_bf16(f0.z); v[3] = (short)to_bf16(f0.w);
      v[4] = (short)to_bf16(f1.x); v[5] = (short)to_bf16(f1.y);
      v[6] = (short)to_bf16(f1.z); v[7] = (short)to_bf16(f1.w);
      *(bf16x8*)&Es[(g * 64 + lane) * 8] = v;
    }
    __syncthreads();
#pragma unroll
    for (int s = 0; s < 4; ++s) {
      int sg = w * 4 + s;
      f32x4 a0 = {0.f, 0.f, 0.f, 0.f}, a1 = {0.f, 0.f, 0.f, 0.f};
      f32x4 a2 = {0.f, 0.f, 0.f, 0.f}, a3 = {0.f, 0.f, 0.f, 0.f};
#pragma unroll
      for (int kc = 0; kc < 4; ++kc) {
        bf16x8 B = *(const bf16x8*)&Es[((sg * 4 + kc) * 64 + lane) * 8];
        a0 = __builtin_amdgcn_mfma_f32_16x16x32_bf16(A[0][kc], B, a0, 0, 0, 0);
        a1 = __builtin_amdgcn_mfma_f32_16x16x32_bf16(A[1][kc], B, a1, 0, 0, 0);
        a2 = __builtin_amdgcn_mfma_f32_16x16x32_bf16(A[2][kc], B, a2, 0, 0, 0);
        a3 = __builtin_amdgcn_mfma_f32_16x16x32_bf16(A[3][kc], B, a3, 0, 0, 0);
      }
#pragma unroll
      for (int r = 0; r < 4; ++r) {
        cnt[0][r] += (a0[r] >= thresh);
        cnt[1][r] += (a1[r] >= thresh);
        cnt[2][r] += (a2[r] >= thresh);
        cnt[3][r] += (a3[r] >= thresh);
      }
    }
    __syncthreads();  // all MFMA reads done before next-chunk overwrite / lcnt reuse
  }

  // cross-wave count reduction in LDS (reuse Es)
  int* lc = (int*)&Es[0];  // lc[0..63] per-query counts, lc[64] flag counter
  if (tid < QT + 1) lc[tid] = 0;
  __syncthreads();
#pragma unroll
  for (int mg = 0; mg < 4; ++mg)
#pragma unroll
    for (int r = 0; r < 4; ++r) {
      int v = cnt[mg][r];
      v += __shfl_xor(v, 1, 64);
      v += __shfl_xor(v, 2, 64);
      v += __shfl_xor(v, 4, 64);
      v += __shfl_xor(v, 8, 64);
      if (am == 0) atomicAdd(&lc[mg * 16 + aq * 4 + r], v);
    }
  __syncthreads();

  // finalize: wave 0 computes D per query and the closed-form contribution
  if (tid < QT) {
    float contrib = 0.f;
    int q = qt * QT + tid;
    if (q < NQL) {
      int li = (q < TL) ? q : q - TL;
      long l = links[2 * li];
      long r = links[2 * li + 1];
      const float4* x = (const float4*)(emb + l * DIM);
      const float4* y = (const float4*)(emb + r * DIM);
      float dot = 0.f, x0 = 0.f, y0 = 0.f;
#pragma unroll
      for (int k = 0; k < 32; ++k) {
        float4 a = x[k], b = y[k];
        if (k == 0) { x0 = a.x; y0 = b.x; }
        dot = fmaf(a.x, b.x, dot);
        dot = fmaf(a.y, b.y, dot);
        dot = fmaf(a.z, b.z, dot);
        dot = fmaf(a.w, b.w, dot);
      }
      float Dq = sqdist_f(dot - 2.0f * x0 * y0, cv, K) + 1.0f;  // + GAMMA
      float acl = acoshf(1.0f + EPSF);
      float clipv = fminf(K * acl * acl, MAXSQ);
      if (lc[tid] >= FLAGTH) {
        contrib = (float)KNEG * fmaxf(Dq - clipv, 0.f);
      } else {
        int p = atomicAdd(&lc[QT], 1);
        list[qt * QT + p] = q;
      }
    }
    contrib = wred_f(contrib);
    if (tid == 0) partial[qt] = contrib * (1.0f / (2.0f * (float)KNEG * (float)TL));
  }
  __syncthreads();
  if (tid == 0) nf[qt] = lc[QT];
}

// ---------- final: sum partials + exact fallback for flagged (normally none) ----------
__launch_bounds__(256)
__global__ void final_kernel(const float* __restrict__ emb, const float* __restrict__ c,
                             const int* __restrict__ links, const float* __restrict__ partial,
                             const int* __restrict__ nf, const int* __restrict__ list,
                             float* __restrict__ out) {
  __shared__ __align__(16) float qvec[DIM];
  __shared__ unsigned short s16[NN];  // 60000 B
  __shared__ int ish[4];
  __shared__ float fsh[4];
  __shared__ float acc_total;
  const int tid = threadIdx.x;

  float t = (tid < QBLK) ? partial[tid] : 0.f;
  t = wred_f(t);
  if ((tid & 63) == 0) fsh[tid >> 6] = t;
  __syncthreads();
  if (tid == 0) acc_total = fsh[0] + fsh[1] + fsh[2] + fsh[3];
  __syncthreads();

  const float cv = c[0];
  const float K = 1.0f / cv;

  for (int qt = 0; qt < QBLK; ++qt) {
    int n = nf[qt];
    for (int j = 0; j < n; ++j) {
      const int q = list[qt * QT + j];
      const int li = (q < TL) ? q : q - TL;
      const int node = (q < TL) ? links[2 * li] : links[2 * li + 1];

      // Dq (redundant per thread, trivial)
      float Dq;
      {
        long l = links[2 * li];
        long r = links[2 * li + 1];
        const float4* x = (const float4*)(emb + l * DIM);
        const float4* y = (const float4*)(emb + r * DIM);
        float dot = 0.f, x0 = 0.f, y0 = 0.f;
#pragma unroll
        for (int k = 0; k < 32; ++k) {
          float4 a = x[k], b = y[k];
          if (k == 0) { x0 = a.x; y0 = b.x; }
          dot = fmaf(a.x, b.x, dot);
          dot = fmaf(a.y, b.y, dot);
          dot = fmaf(a.z, b.z, dot);
          dot = fmaf(a.w, b.w, dot);
        }
        Dq = sqdist_f(dot - 2.0f * x0 * y0, cv, K) + 1.0f;
      }

      if (tid < DIM) qvec[tid] = emb[(long)node * DIM + tid];
      __syncthreads();
      const float q0 = qvec[0];
      const float4* q4 = (const float4*)qvec;

      for (int jj = tid; jj < NN; jj += 256) {
        const float4* row = (const float4*)(emb + (long)jj * DIM);
        float acc = 0.f, e0 = 0.f;
#pragma unroll
        for (int k = 0; k < DIM / 4; ++k) {
          float4 e = row[k];
          float4 v = q4[k];
          if (k == 0) e0 = e.x;
          acc = fmaf(e.x, v.x, acc);
          acc = fmaf(e.y, v.y, acc);
          acc = fmaf(e.z, v.z, acc);
          acc = fmaf(e.w, v.w, acc);
        }
        float s = sqdist_f(acc - 2.0f * e0 * q0, cv, K);
        s16[jj] = __half_as_ushort(__float2half_rn(s));
      }
      __syncthreads();

      unsigned int lo = 0, hi = 0xFFFFu;
      while (lo < hi) {
        unsigned int mid = (lo + hi) >> 1;
        int cnt = 0;
        for (int jj = tid; jj < NN; jj += 256) cnt += (s16[jj] <= mid) ? 1 : 0;
        cnt = wred_i(cnt);
        if ((tid & 63) == 0) ish[tid >> 6] = cnt;
        __syncthreads();
        int tot = ish[0] + ish[1] + ish[2] + ish[3];
        if (tot >= KNEG) hi = mid; else lo = mid + 1;
        __syncthreads();
      }
      const unsigned int T = lo;
      const float Tval = __half2float(__ushort_as_half((unsigned short)T));

      int nl = 0;
      float sum = 0.f;
      for (int jj = tid; jj < NN; jj += 256) {
        unsigned short k = s16[jj];
        if ((unsigned int)k < T) {
          nl++;
          sum += fmaxf(Dq - __half2float(__ushort_as_half(k)), 0.f);
        }
      }
      nl = wred_i(nl);
      sum = wred_f(sum);
      if ((tid & 63) == 0) { ish[tid >> 6] = nl; fsh[tid >> 6] = sum; }
      __syncthreads();
      if (tid == 0) {
        int n_less = ish[0] + ish[1] + ish[2] + ish[3];
        float s = fsh[0] + fsh[1] + fsh[2] + fsh[3];
        s += (float)(KNEG - n_less) * fmaxf(Dq - Tval, 0.f);
        acc_total += s * (1.0f / (2.0f * (float)KNEG * (float)TL));
      }
      __syncthreads();
    }
  }
  if (tid == 0) out[0] = acc_total;
}

extern "C" void kernel_launch(void* const* d_in, const int* in_sizes, int n_in,
                              void* d_out, int out_size, void* d_ws, size_t ws_size,
                              hipStream_t stream) {
  const float* emb = (const float*)d_in[0];
  const float* c = (const float*)d_in[1];
  const int* links = (const int*)d_in[2];
  float* out = (float*)d_out;

  float* partial = (float*)d_ws;          // 94 floats
  int* nf = (int*)(partial + QBLK);       // 94 ints
  int* list = nf + QBLK;                  // 94*64 ints

  gemm_cf<<<QBLK, 256, 0, stream>>>(emb, c, links, partial, nf, list);
  final_kernel<<<1, 256, 0, stream>>>(emb, c, links, partial, nf, list, out);
}